// Round 7
// baseline (221.278 us; speedup 1.0000x reference)
//
#include <hip/hip_runtime.h>
#include <hip/hip_bf16.h>

#define BLOCK   512     // 8 waves; wave w owns channels w*16..w*16+15, all 4 gates
#define NSAMP   32      // samples per block = 2 sample-tiles of 16
#define HDIM    128
#define DDIM    16
#define NOBJ    6
#define NSLOT   16      // shared h/c slot pool

typedef __attribute__((ext_vector_type(8))) short bf16x8;
typedef __attribute__((ext_vector_type(4))) float f32x4;

constexpr int pc6(int m)  { int c = 0; for (int i = 0; i < 6; ++i) c += (m >> i) & 1; return c; }
constexpr int msb6(int m) { int b = -1; for (int i = 0; i < 6; ++i) if (m & (1 << i)) b = i; return b; }

// Compile-time BFS plan with 16-slot allocator (verified in R6).
struct NodeRec { int jo, ps, sl; };
struct Plan { int cnt[7]; int n1[7]; NodeRec nd[7][20]; };
constexpr Plan make_plan() {
    Plan P{};
    int slotOf[64] = {};
    bool busy[NSLOT] = {};
    for (int d = 1; d <= 6; ++d) {
        int n = 0;
        for (int M = 1; M < 64; ++M) {            // phase 1a: leaf children
            if (pc6(M) != d || msb6(M) != 5) continue;
            P.nd[d][n].jo = 5;
            P.nd[d][n].ps = (d == 1) ? -1 : slotOf[M & ~(1 << 5)];
            P.nd[d][n].sl = -1;
            ++n;
        }
        int pend[20] = {}; int np = 0;            // phase 1b: childful into free slots
        for (int M = 1; M < 64; ++M) {
            if (pc6(M) != d || msb6(M) >= 5) continue;
            const int hi = msb6(M);
            int fs = -1;
            for (int s = 0; s < NSLOT; ++s) if (!busy[s]) { fs = s; break; }
            if (fs >= 0) {
                busy[fs] = true; slotOf[M] = fs;
                P.nd[d][n].jo = hi;
                P.nd[d][n].ps = (d == 1) ? -1 : slotOf[M & ~(1 << hi)];
                P.nd[d][n].sl = fs;
                ++n;
            } else pend[np++] = M;
        }
        P.n1[d] = n;
        int freeds[20] = {}; int nf = 0;          // phase 2: reuse msb==4 parents' slots
        if (d >= 2)
            for (int M = 1; M < 64; ++M)
                if (pc6(M) == d - 1 && msb6(M) == 4) freeds[nf++] = slotOf[M];
        for (int i = 0; i < np; ++i) {
            const int M = pend[i]; const int hi = msb6(M);
            const int s = freeds[--nf];
            slotOf[M] = s;
            P.nd[d][n].jo = hi;
            P.nd[d][n].ps = slotOf[M & ~(1 << hi)];
            P.nd[d][n].sl = s;
            ++n;
        }
        P.cnt[d] = n;
        for (int s = 0; s < NSLOT; ++s) busy[s] = false;
        for (int M = 1; M < 64; ++M)
            if (pc6(M) == d && msb6(M) < 5) busy[slotOf[M]] = true;
    }
    return P;
}
constexpr Plan PL = make_plan();

#define LOG2E   1.44269504f
#define TWOL2E  2.88539008f
#define SLOT_SH (16 * NSAMP * 8)   // shorts per slot (8 KB)

__device__ __forceinline__ float fast_sig(float z) {
    float e = __builtin_amdgcn_exp2f(-LOG2E * z);
    return __builtin_amdgcn_rcpf(1.0f + e);
}
__device__ __forceinline__ float fast_tanh(float z) {
    float e = __builtin_amdgcn_exp2f(TWOL2E * z);
    float r = __builtin_amdgcn_rcpf(1.0f + e);
    return fmaf(-2.0f, r, 1.0f);
}
__device__ __forceinline__ unsigned short f2bf(float x) {
    union { float f; unsigned int u; } a; a.f = x;
    unsigned int r = (a.u + 0x7FFFu + ((a.u >> 16) & 1u)) >> 16;
    return (unsigned short)r;
}
__device__ __forceinline__ unsigned pk2(float a, float b) {
    union { __hip_bfloat162 h; unsigned u; } z;
    z.h = __float22bfloat162_rn(float2{a, b});
    return z.u;
}
__device__ __forceinline__ float bflo(unsigned p) {
    union { unsigned u; float f; } a; a.u = p << 16; return a.f;
}
__device__ __forceinline__ float bfhi(unsigned p) {
    union { unsigned u; float f; } a; a.u = p & 0xFFFF0000u; return a.f;
}

// LDS h layout: hs[((slot*16 + kslot)*NSAMP + n)*8 + j] = h[ch = kslot*8+j][sample n]
// B-frag (chunk q, tile st), lane (quad,m16): kslot = q*4+quad, n = st*16+m16 -> b128.
// Wave w writes ch = w*16+quad*4+r at kslot = w*2+(quad>>1), j = (quad&1)*4+r.

__global__ __launch_bounds__(BLOCK, 2)   // VGPR cap 256 (known-good); 1 block/CU (LDS 137 KB)
void subset_lstm_n32_kernel(
    const float* __restrict__ x_input,
    const float* __restrict__ W_ih,
    const float* __restrict__ W_hh,
    const float* __restrict__ b_ih,
    const float* __restrict__ b_hh,
    const float* __restrict__ fc1_W,
    const float* __restrict__ fc1_b,
    const float* __restrict__ fc2_W,
    const float* __restrict__ fc2_b,
    float* __restrict__ out)
{
    __shared__ __align__(16) unsigned short hs[NSLOT * SLOT_SH];        // 128 KB
    __shared__ __align__(16) unsigned short xb[NOBJ * 2 * NSAMP * 8];   // 6 KB
    __shared__ __align__(16) unsigned short xpad[16];
    float* s_maxh  = (float*)hs;                  // 16 KB  (post-LSTM alias)
    float* s_fc1   = (float*)(hs + 8192);         // 32 KB  (post-LSTM alias)
    float* s_logit = (float*)xb;

    const int t      = threadIdx.x;
    const int w      = t >> 6;
    const int lane   = t & 63;
    const int quad   = lane >> 4;
    const int m16    = lane & 15;
    const int s_base = blockIdx.x * NSAMP;

    if (t < 16) xpad[t] = (t == 0) ? f2bf(1.0f) : (unsigned short)0;

    // ---- x B-chunks (quads 0,1; quads 2,3 from xpad) ----
    for (int idx = t; idx < NOBJ * 2 * NSAMP * 8; idx += BLOCK) {
        const int j = idx & 7, n = (idx >> 3) & 31, q = (idx >> 8) & 1, obj = idx >> 9;
        xb[idx] = f2bf(x_input[(s_base + n) * (NOBJ * DDIM) + obj * DDIM + q * 8 + j]);
    }

    // ---- persistent A-frags wf[gate][chunk]: row r = g*128 + w*16 + m16 ----
    // chunk 4 = x-projection with bias folded at (quad2, j0) against B's 1.0
    bf16x8 wf[4][5];
    #pragma unroll
    for (int g = 0; g < 4; ++g) {
        const int grow = g * HDIM + w * 16 + m16;
        const float* whr = W_hh + grow * HDIM;
        const float* wir = W_ih + grow * DDIM;
        #pragma unroll
        for (int q = 0; q < 4; ++q) {
            union { unsigned short u[8]; bf16x8 v; } pk;
            #pragma unroll
            for (int j = 0; j < 8; ++j)
                pk.u[j] = f2bf(whr[q * 32 + quad * 8 + j]);
            wf[g][q] = pk.v;
        }
        {
            union { unsigned short u[8]; bf16x8 v; } pk;
            #pragma unroll
            for (int j = 0; j < 8; ++j) {
                float v = 0.0f;
                if (quad < 2) v = wir[quad * 8 + j];
                else if (quad == 2 && j == 0) v = b_ih[grow] + b_hh[grow];
                pk.u[j] = f2bf(v);
            }
            wf[g][4] = pk.v;
        }
    }

    uint2 cs[NSLOT][2];   // c-state, bf16-packed (r0r1, r2r3), static indices
    float mh[2][4];
    #pragma unroll
    for (int st = 0; st < 2; ++st)
        #pragma unroll
        for (int r = 0; r < 4; ++r) mh[st][r] = -1e30f;

    const int kslot = w * 2 + (quad >> 1);

    #pragma unroll
    for (int d = 1; d <= 6; ++d) {
        __syncthreads();
        #pragma unroll
        for (int ni = 0; ni < PL.cnt[d]; ++ni) {
            if (ni == PL.n1[d]) __syncthreads();   // slot-recycle barrier (constexpr)
            const int jo = PL.nd[d][ni].jo;
            const int ps = PL.nd[d][ni].ps;
            const int sl = PL.nd[d][ni].sl;

            f32x4 acc[4][2];
            #pragma unroll
            for (int g = 0; g < 4; ++g)
                #pragma unroll
                for (int st = 0; st < 2; ++st)
                    acc[g][st] = f32x4{0.f, 0.f, 0.f, 0.f};

            #pragma unroll
            for (int st = 0; st < 2; ++st) {   // x + bias chunk
                const unsigned short* bp = (quad < 2)
                    ? &xb[((jo * 2 + quad) * NSAMP + st * 16 + m16) * 8]
                    : &xpad[(quad - 2) * 8];
                const bf16x8 bfx = *(const bf16x8*)bp;
                #pragma unroll
                for (int g = 0; g < 4; ++g)
                    acc[g][st] = __builtin_amdgcn_mfma_f32_16x16x32_bf16(
                        wf[g][4], bfx, acc[g][st], 0, 0, 0);
            }
            if (ps >= 0) {
                #pragma unroll
                for (int q = 0; q < 4; ++q)
                    #pragma unroll
                    for (int st = 0; st < 2; ++st) {
                        const bf16x8 bh = *(const bf16x8*)
                            &hs[((ps * 16 + q * 4 + quad) * NSAMP + st * 16 + m16) * 8];
                        #pragma unroll
                        for (int g = 0; g < 4; ++g)
                            acc[g][st] = __builtin_amdgcn_mfma_f32_16x16x32_bf16(
                                wf[g][q], bh, acc[g][st], 0, 0, 0);
                    }
            }

            // pointwise: channel c = w*16 + quad*4 + r, sample = st*16 + m16
            #pragma unroll
            for (int st = 0; st < 2; ++st) {
                float cn4[4], hn4[4];
                #pragma unroll
                for (int r = 0; r < 4; ++r) {
                    float cprev = 0.0f;
                    if (ps >= 0) {
                        const unsigned p = (r < 2) ? cs[ps][st].x : cs[ps][st].y;
                        cprev = (r & 1) ? bfhi(p) : bflo(p);
                    }
                    const float ig = fast_sig(acc[0][st][r]);
                    const float fg = fast_sig(acc[1][st][r]);
                    const float gg = fast_tanh(acc[2][st][r]);
                    const float og = fast_sig(acc[3][st][r]);
                    const float cn = fmaf(fg, cprev, ig * gg);
                    const float h  = og * fast_tanh(cn);
                    cn4[r] = cn; hn4[r] = h;
                    mh[st][r] = fmaxf(mh[st][r], h);
                }
                if (sl >= 0) {
                    cs[sl][st].x = pk2(cn4[0], cn4[1]);
                    cs[sl][st].y = pk2(cn4[2], cn4[3]);
                    union { __hip_bfloat162 h2[2]; uint2 v; } hp;
                    hp.h2[0] = __float22bfloat162_rn(float2{hn4[0], hn4[1]});
                    hp.h2[1] = __float22bfloat162_rn(float2{hn4[2], hn4[3]});
                    *(uint2*)&hs[((sl * 16 + kslot) * NSAMP + st * 16 + m16) * 8
                                 + (quad & 1) * 4] = hp.v;
                }
            }
        }
    }

    __syncthreads();   // h slots dead; reuse hs for epilogue
    #pragma unroll
    for (int st = 0; st < 2; ++st) {
        float4 v; v.x = mh[st][0]; v.y = mh[st][1]; v.z = mh[st][2]; v.w = mh[st][3];
        *(float4*)&s_maxh[(st * 16 + m16) * HDIM + w * 16 + quad * 4] = v;
    }
    __syncthreads();

    // ---- FC1: f = t&255, sample half t>>8 (16 samples each) ----
    {
        const int f  = t & 255;
        const int sh = t >> 8;          // 0/1
        float a1[16];
        #pragma unroll
        for (int s = 0; s < 16; ++s) a1[s] = fc1_b[f];
        for (int k4 = 0; k4 < HDIM / 4; ++k4) {
            const float4 wv = *(const float4*)&fc1_W[f * HDIM + k4 * 4];
            #pragma unroll
            for (int s = 0; s < 16; ++s) {
                const float4 h4 = *(const float4*)&s_maxh[(sh * 16 + s) * HDIM + k4 * 4];
                a1[s] += wv.x * h4.x + wv.y * h4.y + wv.z * h4.z + wv.w * h4.w;
            }
        }
        #pragma unroll
        for (int s = 0; s < 16; ++s)
            s_fc1[(sh * 16 + s) * 256 + f] = fmaxf(a1[s], 0.0f);
    }
    __syncthreads();

    if (t < NSAMP * 10) {
        const int s = t / 10, a = t % 10;
        float acc2 = fc2_b[a];
        for (int f4 = 0; f4 < 256 / 4; ++f4) {
            const float4 wv = *(const float4*)&fc2_W[a * 256 + f4 * 4];
            const float4 v  = *(const float4*)&s_fc1[s * 256 + f4 * 4];
            acc2 += wv.x * v.x + wv.y * v.y + wv.z * v.z + wv.w * v.w;
        }
        s_logit[s * 10 + a] = acc2;
    }
    __syncthreads();

    if (t < NSAMP) {
        float m = -1e30f;
        #pragma unroll
        for (int a = 0; a < 10; ++a) m = fmaxf(m, s_logit[t * 10 + a]);
        float sum = 0.0f;
        #pragma unroll
        for (int a = 0; a < 10; ++a) sum += __expf(s_logit[t * 10 + a] - m);
        const float lse = m + __logf(sum);
        #pragma unroll
        for (int a = 0; a < 10; ++a)
            out[(s_base + t) * 10 + a] = s_logit[t * 10 + a] - lse;
    }
}

extern "C" void kernel_launch(void* const* d_in, const int* in_sizes, int n_in,
                              void* d_out, int out_size, void* d_ws, size_t ws_size,
                              hipStream_t stream)
{
    (void)d_ws; (void)ws_size; (void)n_in; (void)out_size;

    const float* x   = (const float*)d_in[0];
    const float* Wih = (const float*)d_in[1];
    const float* Whh = (const float*)d_in[2];
    const float* bih = (const float*)d_in[3];
    const float* bhh = (const float*)d_in[4];
    const float* f1w = (const float*)d_in[5];
    const float* f1b = (const float*)d_in[6];
    const float* f2w = (const float*)d_in[7];
    const float* f2b = (const float*)d_in[8];

    const int mb = in_sizes[0] / (NOBJ * DDIM);   // 8192
    dim3 grid(mb / NSAMP), block(BLOCK);
    subset_lstm_n32_kernel<<<grid, block, 0, stream>>>(
        x, Wih, Whh, bih, bhh, f1w, f1b, f2w, f2b, (float*)d_out);
}

// Round 8
// 207.488 us; speedup vs baseline: 1.0665x; 1.0665x over previous
//
#include <hip/hip_runtime.h>
#include <hip/hip_bf16.h>

#define BLOCK   512     // 8 waves; wave w owns channels w*16..w*16+15, all 4 gates
#define NSAMP   16
#define HDIM    128
#define DDIM    16
#define NOBJ    6
#define NSLOT   16

typedef __attribute__((ext_vector_type(8))) short bf16x8;
typedef __attribute__((ext_vector_type(4))) float f32x4;

constexpr int pc6(int m)  { int c = 0; for (int i = 0; i < 6; ++i) c += (m >> i) & 1; return c; }
constexpr int msb6(int m) { int b = -1; for (int i = 0; i < 6; ++i) if (m & (1 << i)) b = i; return b; }

// Compile-time BFS plan with 16-slot allocator (verified R6/R7).
struct NodeRec { int jo, ps, sl; };
struct Plan { int cnt[7]; int n1[7]; NodeRec nd[7][20]; };
constexpr Plan make_plan() {
    Plan P{};
    int slotOf[64] = {};
    bool busy[NSLOT] = {};
    for (int d = 1; d <= 6; ++d) {
        int n = 0;
        for (int M = 1; M < 64; ++M) {            // phase 1a: leaf children
            if (pc6(M) != d || msb6(M) != 5) continue;
            P.nd[d][n].jo = 5;
            P.nd[d][n].ps = (d == 1) ? -1 : slotOf[M & ~(1 << 5)];
            P.nd[d][n].sl = -1;
            ++n;
        }
        int pend[20] = {}; int np = 0;            // phase 1b: childful into free slots
        for (int M = 1; M < 64; ++M) {
            if (pc6(M) != d || msb6(M) >= 5) continue;
            const int hi = msb6(M);
            int fs = -1;
            for (int s = 0; s < NSLOT; ++s) if (!busy[s]) { fs = s; break; }
            if (fs >= 0) {
                busy[fs] = true; slotOf[M] = fs;
                P.nd[d][n].jo = hi;
                P.nd[d][n].ps = (d == 1) ? -1 : slotOf[M & ~(1 << hi)];
                P.nd[d][n].sl = fs;
                ++n;
            } else pend[np++] = M;
        }
        P.n1[d] = n;
        int freeds[20] = {}; int nf = 0;          // phase 2: reuse msb==4 parents' slots
        if (d >= 2)
            for (int M = 1; M < 64; ++M)
                if (pc6(M) == d - 1 && msb6(M) == 4) freeds[nf++] = slotOf[M];
        for (int i = 0; i < np; ++i) {
            const int M = pend[i]; const int hi = msb6(M);
            const int s = freeds[--nf];
            slotOf[M] = s;
            P.nd[d][n].jo = hi;
            P.nd[d][n].ps = slotOf[M & ~(1 << hi)];
            P.nd[d][n].sl = s;
            ++n;
        }
        P.cnt[d] = n;
        for (int s = 0; s < NSLOT; ++s) busy[s] = false;
        for (int M = 1; M < 64; ++M)
            if (pc6(M) == d && msb6(M) < 5) busy[slotOf[M]] = true;
    }
    return P;
}
constexpr Plan PL = make_plan();

#define LOG2E   1.44269504f
#define TWOL2E  2.88539008f
#define SLOT_SH (16 * NSAMP * 8)   // 2048 shorts = 4 KB per slot

__device__ __forceinline__ unsigned short f2bf(float x) {
    union { float f; unsigned int u; } a; a.f = x;
    unsigned int r = (a.u + 0x7FFFu + ((a.u >> 16) & 1u)) >> 16;
    return (unsigned short)r;
}
__device__ __forceinline__ unsigned pk2(float a, float b) {
    union { __hip_bfloat162 h; unsigned u; } z;
    z.h = __float22bfloat162_rn(float2{a, b});
    return z.u;
}
__device__ __forceinline__ float bflo(unsigned p) {
    union { unsigned u; float f; } a; a.u = p << 16; return a.f;
}
__device__ __forceinline__ float bfhi(unsigned p) {
    union { unsigned u; float f; } a; a.u = p & 0xFFFF0000u; return a.f;
}
// z already pre-scaled by -log2e (sig) / 2log2e (tanh) via the weights
__device__ __forceinline__ float sig_pre(float zp) {
    return __builtin_amdgcn_rcpf(1.0f + __builtin_amdgcn_exp2f(zp));
}
__device__ __forceinline__ float tanh_pre(float zp) {
    float r = __builtin_amdgcn_rcpf(1.0f + __builtin_amdgcn_exp2f(zp));
    return fmaf(-2.0f, r, 1.0f);
}

// LDS h layout: hs[((slot*16 + kslot)*NSAMP + n)*8 + j] = h[ch = kslot*8+j][sample n]
// B-frag chunk q, lane (quad,m16): kslot = q*4+quad -> 16B-aligned ds_read_b128.
// Wave w writes ch = w*16+quad*4+r at kslot = w*2+(quad>>1), j = (quad&1)*4+r.

__global__ __launch_bounds__(BLOCK)
__attribute__((amdgpu_waves_per_eu(2, 2)))   // pin 2 waves/EU: 256-VGPR budget, no heuristic spill
void subset_lstm_pair_kernel(
    const float* __restrict__ x_input,
    const float* __restrict__ W_ih,
    const float* __restrict__ W_hh,
    const float* __restrict__ b_ih,
    const float* __restrict__ b_hh,
    const float* __restrict__ fc1_W,
    const float* __restrict__ fc1_b,
    const float* __restrict__ fc2_W,
    const float* __restrict__ fc2_b,
    float* __restrict__ out)
{
    __shared__ __align__(16) unsigned short hs[NSLOT * SLOT_SH];        // 64 KB
    __shared__ __align__(16) unsigned short xb[NOBJ * 2 * NSAMP * 8];   // 3 KB
    __shared__ __align__(16) unsigned short xpad[16];
    float* s_maxh  = (float*)hs;                 // 8 KB  (post-LSTM alias)
    float* s_fc1   = (float*)(hs + 4096);        // 16 KB (post-LSTM alias)
    float* s_logit = (float*)xb;

    const int t      = threadIdx.x;
    const int w      = t >> 6;
    const int lane   = t & 63;
    const int quad   = lane >> 4;
    const int m16    = lane & 15;
    const int s_base = blockIdx.x * NSAMP;

    if (t < 16) xpad[t] = (t == 0) ? f2bf(1.0f) : (unsigned short)0;

    // ---- x B-chunks (quads 0,1; quads 2,3 from xpad) ----
    for (int idx = t; idx < NOBJ * 2 * NSAMP * 8; idx += BLOCK) {
        const int j = idx & 7, n = (idx >> 3) & 15, q = (idx >> 7) & 1, obj = idx >> 8;
        xb[idx] = f2bf(x_input[(s_base + n) * (NOBJ * DDIM) + obj * DDIM + q * 8 + j]);
    }

    // ---- persistent A-frags wf[gate][chunk], PRE-SCALED by activation constants ----
    // gates i,f,o: row *= -log2e ; gate g: row *= 2*log2e. Bias folded at (quad2,j0).
    bf16x8 wf[4][5];
    #pragma unroll
    for (int g = 0; g < 4; ++g) {
        const float sc = (g == 2) ? TWOL2E : -LOG2E;
        const int grow = g * HDIM + w * 16 + m16;
        const float* whr = W_hh + grow * HDIM;
        const float* wir = W_ih + grow * DDIM;
        #pragma unroll
        for (int q = 0; q < 4; ++q) {
            union { unsigned short u[8]; bf16x8 v; } pk;
            #pragma unroll
            for (int j = 0; j < 8; ++j)
                pk.u[j] = f2bf(sc * whr[q * 32 + quad * 8 + j]);
            wf[g][q] = pk.v;
        }
        {
            union { unsigned short u[8]; bf16x8 v; } pk;
            #pragma unroll
            for (int j = 0; j < 8; ++j) {
                float v = 0.0f;
                if (quad < 2) v = sc * wir[quad * 8 + j];
                else if (quad == 2 && j == 0) v = sc * (b_ih[grow] + b_hh[grow]);
                pk.u[j] = f2bf(v);
            }
            wf[g][4] = pk.v;
        }
    }

    uint2 cs[NSLOT];   // c-state: 4 bf16 per lane (r0r1, r2r3), static slot indices
    float mh[4] = {-1e30f, -1e30f, -1e30f, -1e30f};
    const int kslot = w * 2 + (quad >> 1);

    #pragma unroll
    for (int d = 1; d <= 6; ++d) {
        __syncthreads();
        #pragma unroll
        for (int seg = 0; seg < 2; ++seg) {
            const int sBeg = seg ? PL.n1[d] : 0;
            const int sEnd = seg ? PL.cnt[d] : PL.n1[d];
            if (seg && sBeg >= sEnd) continue;
            if (seg) __syncthreads();   // slot-recycle barrier (L3 only, constexpr)

            #pragma unroll
            for (int ni = sBeg; ni < sEnd; ni += 2) {
                f32x4 acc[2][4];
                // ---- MFMA phase for both pair members (independent) ----
                #pragma unroll
                for (int e = 0; e < 2; ++e) {
                    if (ni + e >= sEnd) continue;
                    const int jo = PL.nd[d][ni + e].jo;
                    const int ps = PL.nd[d][ni + e].ps;
                    #pragma unroll
                    for (int g = 0; g < 4; ++g)
                        acc[e][g] = f32x4{0.f, 0.f, 0.f, 0.f};
                    const unsigned short* bp = (quad < 2)
                        ? &xb[((jo * 2 + quad) * NSAMP + m16) * 8]
                        : &xpad[(quad - 2) * 8];
                    const bf16x8 bfx = *(const bf16x8*)bp;
                    #pragma unroll
                    for (int g = 0; g < 4; ++g)
                        acc[e][g] = __builtin_amdgcn_mfma_f32_16x16x32_bf16(
                            wf[g][4], bfx, acc[e][g], 0, 0, 0);
                    if (ps >= 0) {
                        #pragma unroll
                        for (int q = 0; q < 4; ++q) {
                            const bf16x8 bh = *(const bf16x8*)
                                &hs[((ps * 16 + q * 4 + quad) * NSAMP + m16) * 8];
                            #pragma unroll
                            for (int g = 0; g < 4; ++g)
                                acc[e][g] = __builtin_amdgcn_mfma_f32_16x16x32_bf16(
                                    wf[g][q], bh, acc[e][g], 0, 0, 0);
                        }
                    }
                }
                // ---- pointwise phase (overlaps e=1 MFMAs in flight) ----
                #pragma unroll
                for (int e = 0; e < 2; ++e) {
                    if (ni + e >= sEnd) continue;
                    const int ps = PL.nd[d][ni + e].ps;
                    const int sl = PL.nd[d][ni + e].sl;
                    float cn4[4], hn4[4];
                    #pragma unroll
                    for (int r = 0; r < 4; ++r) {
                        float cprev = 0.0f;
                        if (ps >= 0) {
                            const unsigned p = (r < 2) ? cs[ps].x : cs[ps].y;
                            cprev = (r & 1) ? bfhi(p) : bflo(p);
                        }
                        const float ig = sig_pre(acc[e][0][r]);
                        const float fg = sig_pre(acc[e][1][r]);
                        const float gg = tanh_pre(acc[e][2][r]);
                        const float og = sig_pre(acc[e][3][r]);
                        const float cn = fmaf(fg, cprev, ig * gg);
                        const float h  = og * tanh_pre(TWOL2E * cn);
                        cn4[r] = cn; hn4[r] = h;
                        mh[r] = fmaxf(mh[r], h);
                    }
                    if (sl >= 0) {
                        cs[sl].x = pk2(cn4[0], cn4[1]);
                        cs[sl].y = pk2(cn4[2], cn4[3]);
                        union { __hip_bfloat162 h2[2]; uint2 v; } hp;
                        hp.h2[0] = __float22bfloat162_rn(float2{hn4[0], hn4[1]});
                        hp.h2[1] = __float22bfloat162_rn(float2{hn4[2], hn4[3]});
                        *(uint2*)&hs[((sl * 16 + kslot) * NSAMP + m16) * 8
                                     + (quad & 1) * 4] = hp.v;
                    }
                }
            }
        }
    }

    __syncthreads();   // h slots dead; reuse hs for epilogue
    {
        float4 v; v.x = mh[0]; v.y = mh[1]; v.z = mh[2]; v.w = mh[3];
        *(float4*)&s_maxh[m16 * HDIM + w * 16 + quad * 4] = v;
    }
    __syncthreads();

    // ---- FC1: f = t&255, sample half t>>8 (8 samples each) ----
    {
        const int f  = t & 255;
        const int sh = t >> 8;
        float a1[8];
        #pragma unroll
        for (int s = 0; s < 8; ++s) a1[s] = fc1_b[f];
        for (int k4 = 0; k4 < HDIM / 4; ++k4) {
            const float4 wv = *(const float4*)&fc1_W[f * HDIM + k4 * 4];
            #pragma unroll
            for (int s = 0; s < 8; ++s) {
                const float4 h4 = *(const float4*)&s_maxh[(sh * 8 + s) * HDIM + k4 * 4];
                a1[s] += wv.x * h4.x + wv.y * h4.y + wv.z * h4.z + wv.w * h4.w;
            }
        }
        #pragma unroll
        for (int s = 0; s < 8; ++s)
            s_fc1[(sh * 8 + s) * 256 + f] = fmaxf(a1[s], 0.0f);
    }
    __syncthreads();

    if (t < NSAMP * 10) {
        const int s = t / 10, a = t % 10;
        float acc2 = fc2_b[a];
        for (int f4 = 0; f4 < 256 / 4; ++f4) {
            const float4 wv = *(const float4*)&fc2_W[a * 256 + f4 * 4];
            const float4 v  = *(const float4*)&s_fc1[s * 256 + f4 * 4];
            acc2 += wv.x * v.x + wv.y * v.y + wv.z * v.z + wv.w * v.w;
        }
        s_logit[s * 10 + a] = acc2;
    }
    __syncthreads();

    if (t < NSAMP) {
        float m = -1e30f;
        #pragma unroll
        for (int a = 0; a < 10; ++a) m = fmaxf(m, s_logit[t * 10 + a]);
        float sum = 0.0f;
        #pragma unroll
        for (int a = 0; a < 10; ++a) sum += __expf(s_logit[t * 10 + a] - m);
        const float lse = m + __logf(sum);
        #pragma unroll
        for (int a = 0; a < 10; ++a)
            out[(s_base + t) * 10 + a] = s_logit[t * 10 + a] - lse;
    }
}

extern "C" void kernel_launch(void* const* d_in, const int* in_sizes, int n_in,
                              void* d_out, int out_size, void* d_ws, size_t ws_size,
                              hipStream_t stream)
{
    (void)d_ws; (void)ws_size; (void)n_in; (void)out_size;

    const float* x   = (const float*)d_in[0];
    const float* Wih = (const float*)d_in[1];
    const float* Whh = (const float*)d_in[2];
    const float* bih = (const float*)d_in[3];
    const float* bhh = (const float*)d_in[4];
    const float* f1w = (const float*)d_in[5];
    const float* f1b = (const float*)d_in[6];
    const float* f2w = (const float*)d_in[7];
    const float* f2b = (const float*)d_in[8];

    const int mb = in_sizes[0] / (NOBJ * DDIM);   // 8192
    dim3 grid(mb / NSAMP), block(BLOCK);
    subset_lstm_pair_kernel<<<grid, block, 0, stream>>>(
        x, Wih, Whh, bih, bhh, f1w, f1b, f2w, f2b, (float*)d_out);
}

// Round 9
// 204.235 us; speedup vs baseline: 1.0835x; 1.0159x over previous
//
#include <hip/hip_runtime.h>
#include <hip/hip_bf16.h>

#define BLOCK   512     // 8 waves; wave w owns channels w*16..w*16+15, all 4 gates
#define NSAMP   16
#define HDIM    128
#define DDIM    16
#define NOBJ    6
#define NSLOT   16

typedef __attribute__((ext_vector_type(8))) short bf16x8;
typedef __attribute__((ext_vector_type(4))) float f32x4;

constexpr int pc6(int m)  { int c = 0; for (int i = 0; i < 6; ++i) c += (m >> i) & 1; return c; }
constexpr int msb6(int m) { int b = -1; for (int i = 0; i < 6; ++i) if (m & (1 << i)) b = i; return b; }

// Compile-time BFS plan with 16-slot allocator (verified R6-R8).
struct NodeRec { int jo, ps, sl; };
struct Plan { int cnt[7]; int n1[7]; NodeRec nd[7][20]; };
constexpr Plan make_plan() {
    Plan P{};
    int slotOf[64] = {};
    bool busy[NSLOT] = {};
    for (int d = 1; d <= 6; ++d) {
        int n = 0;
        for (int M = 1; M < 64; ++M) {            // phase 1a: leaf children
            if (pc6(M) != d || msb6(M) != 5) continue;
            P.nd[d][n].jo = 5;
            P.nd[d][n].ps = (d == 1) ? -1 : slotOf[M & ~(1 << 5)];
            P.nd[d][n].sl = -1;
            ++n;
        }
        int pend[20] = {}; int np = 0;            // phase 1b: childful into free slots
        for (int M = 1; M < 64; ++M) {
            if (pc6(M) != d || msb6(M) >= 5) continue;
            const int hi = msb6(M);
            int fs = -1;
            for (int s = 0; s < NSLOT; ++s) if (!busy[s]) { fs = s; break; }
            if (fs >= 0) {
                busy[fs] = true; slotOf[M] = fs;
                P.nd[d][n].jo = hi;
                P.nd[d][n].ps = (d == 1) ? -1 : slotOf[M & ~(1 << hi)];
                P.nd[d][n].sl = fs;
                ++n;
            } else pend[np++] = M;
        }
        P.n1[d] = n;
        int freeds[20] = {}; int nf = 0;          // phase 2: reuse msb==4 parents' slots
        if (d >= 2)
            for (int M = 1; M < 64; ++M)
                if (pc6(M) == d - 1 && msb6(M) == 4) freeds[nf++] = slotOf[M];
        for (int i = 0; i < np; ++i) {
            const int M = pend[i]; const int hi = msb6(M);
            const int s = freeds[--nf];
            slotOf[M] = s;
            P.nd[d][n].jo = hi;
            P.nd[d][n].ps = slotOf[M & ~(1 << hi)];
            P.nd[d][n].sl = s;
            ++n;
        }
        P.cnt[d] = n;
        for (int s = 0; s < NSLOT; ++s) busy[s] = false;
        for (int M = 1; M < 64; ++M)
            if (pc6(M) == d && msb6(M) < 5) busy[slotOf[M]] = true;
    }
    return P;
}
constexpr Plan PL = make_plan();

#define LOG2E   1.44269504f
#define TWOL2E  2.88539008f
#define SLOT_SH (16 * NSAMP * 8)   // 2048 shorts = 4 KB per slot

__device__ __forceinline__ unsigned short f2bf(float x) {
    union { float f; unsigned int u; } a; a.f = x;
    unsigned int r = (a.u + 0x7FFFu + ((a.u >> 16) & 1u)) >> 16;
    return (unsigned short)r;
}
__device__ __forceinline__ unsigned pk2(float a, float b) {
    union { __hip_bfloat162 h; unsigned u; } z;
    z.h = __float22bfloat162_rn(float2{a, b});
    return z.u;
}
__device__ __forceinline__ float bflo(unsigned p) {
    union { unsigned u; float f; } a; a.u = p << 16; return a.f;
}
__device__ __forceinline__ float bfhi(unsigned p) {
    union { unsigned u; float f; } a; a.u = p & 0xFFFF0000u; return a.f;
}

// LDS h layout: hs[((slot*16 + kslot)*NSAMP + n)*8 + j] = h[ch = kslot*8+j][sample n]
// B-frag chunk q, lane (quad,m16): kslot = q*4+quad -> 16B-aligned ds_read_b128.
// Wave w writes ch = w*16+quad*4+r at kslot = w*2+(quad>>1), j = (quad&1)*4+r.

__global__ __launch_bounds__(BLOCK)
__attribute__((amdgpu_waves_per_eu(2, 4)))   // min 2 (VGPR<=256, no spill), max 4 (allow 2 blocks/CU!)
void subset_lstm_fused_kernel(
    const float* __restrict__ x_input,
    const float* __restrict__ W_ih,
    const float* __restrict__ W_hh,
    const float* __restrict__ b_ih,
    const float* __restrict__ b_hh,
    const float* __restrict__ fc1_W,
    const float* __restrict__ fc1_b,
    const float* __restrict__ fc2_W,
    const float* __restrict__ fc2_b,
    float* __restrict__ out)
{
    __shared__ __align__(16) unsigned short hs[NSLOT * SLOT_SH];        // 64 KB
    __shared__ __align__(16) unsigned short xb[NOBJ * 2 * NSAMP * 8];   // 3 KB
    __shared__ __align__(16) unsigned short xpad[16];
    float* s_maxh  = (float*)hs;                 // 8 KB  (post-LSTM alias)
    float* s_fc1   = (float*)(hs + 4096);        // 16 KB (post-LSTM alias)
    float* s_logit = (float*)xb;

    const int t      = threadIdx.x;
    const int w      = t >> 6;
    const int lane   = t & 63;
    const int quad   = lane >> 4;
    const int m16    = lane & 15;
    const int s_base = blockIdx.x * NSAMP;

    if (t < 16) xpad[t] = (t == 0) ? f2bf(1.0f) : (unsigned short)0;

    // ---- x B-chunks (quads 0,1; quads 2,3 from xpad) ----
    for (int idx = t; idx < NOBJ * 2 * NSAMP * 8; idx += BLOCK) {
        const int j = idx & 7, n = (idx >> 3) & 15, q = (idx >> 7) & 1, obj = idx >> 8;
        xb[idx] = f2bf(x_input[(s_base + n) * (NOBJ * DDIM) + obj * DDIM + q * 8 + j]);
    }

    // ---- persistent A-frags wf[gate][chunk], PRE-SCALED by activation constants ----
    // gates i,f,o: row *= -log2e (so sigma = rcp(1+exp2(z'))) ; gate g: row *= 2*log2e
    // (so tanh = (v-2)/v with v = 1+exp2(z')). Bias folded at (quad2,j0) vs B's 1.0.
    bf16x8 wf[4][5];
    #pragma unroll
    for (int g = 0; g < 4; ++g) {
        const float sc = (g == 2) ? TWOL2E : -LOG2E;
        const int grow = g * HDIM + w * 16 + m16;
        const float* whr = W_hh + grow * HDIM;
        const float* wir = W_ih + grow * DDIM;
        #pragma unroll
        for (int q = 0; q < 4; ++q) {
            union { unsigned short u[8]; bf16x8 v; } pk;
            #pragma unroll
            for (int j = 0; j < 8; ++j)
                pk.u[j] = f2bf(sc * whr[q * 32 + quad * 8 + j]);
            wf[g][q] = pk.v;
        }
        {
            union { unsigned short u[8]; bf16x8 v; } pk;
            #pragma unroll
            for (int j = 0; j < 8; ++j) {
                float v = 0.0f;
                if (quad < 2) v = sc * wir[quad * 8 + j];
                else if (quad == 2 && j == 0) v = sc * (b_ih[grow] + b_hh[grow]);
                pk.u[j] = f2bf(v);
            }
            wf[g][4] = pk.v;
        }
    }

    uint2 cs[NSLOT];   // c-state: 4 bf16 per lane (r0r1, r2r3), static slot indices
    float mh[4] = {-1e30f, -1e30f, -1e30f, -1e30f};
    const int kslot = w * 2 + (quad >> 1);

    #pragma unroll
    for (int d = 1; d <= 6; ++d) {
        __syncthreads();
        #pragma unroll
        for (int seg = 0; seg < 2; ++seg) {
            const int sBeg = seg ? PL.n1[d] : 0;
            const int sEnd = seg ? PL.cnt[d] : PL.n1[d];
            if (seg && sBeg >= sEnd) continue;
            if (seg) __syncthreads();   // slot-recycle barrier (L3 only, constexpr)

            #pragma unroll
            for (int ni = sBeg; ni < sEnd; ni += 2) {
                f32x4 acc[2][4];
                // ---- MFMA phase for both pair members (independent) ----
                #pragma unroll
                for (int e = 0; e < 2; ++e) {
                    if (ni + e >= sEnd) continue;
                    const int jo = PL.nd[d][ni + e].jo;
                    const int ps = PL.nd[d][ni + e].ps;
                    #pragma unroll
                    for (int g = 0; g < 4; ++g)
                        acc[e][g] = f32x4{0.f, 0.f, 0.f, 0.f};
                    const unsigned short* bp = (quad < 2)
                        ? &xb[((jo * 2 + quad) * NSAMP + m16) * 8]
                        : &xpad[(quad - 2) * 8];
                    const bf16x8 bfx = *(const bf16x8*)bp;
                    #pragma unroll
                    for (int g = 0; g < 4; ++g)
                        acc[e][g] = __builtin_amdgcn_mfma_f32_16x16x32_bf16(
                            wf[g][4], bfx, acc[e][g], 0, 0, 0);
                    if (ps >= 0) {
                        #pragma unroll
                        for (int q = 0; q < 4; ++q) {
                            const bf16x8 bh = *(const bf16x8*)
                                &hs[((ps * 16 + q * 4 + quad) * NSAMP + m16) * 8];
                            #pragma unroll
                            for (int g = 0; g < 4; ++g)
                                acc[e][g] = __builtin_amdgcn_mfma_f32_16x16x32_bf16(
                                    wf[g][q], bh, acc[e][g], 0, 0, 0);
                        }
                    }
                }
                // ---- pointwise phase, fused-denominator form (7 trans/update) ----
                // cn = c/q + (v-2)/(u*v) = (c*u*v + q*(v-2)) * rcp(q*u*v)
                // h  = sigma_o * tanh(cn) = (w-2) * rcp(qo*w),  w = 1+exp2(2log2e*cn)
                #pragma unroll
                for (int e = 0; e < 2; ++e) {
                    if (ni + e >= sEnd) continue;
                    const int ps = PL.nd[d][ni + e].ps;
                    const int sl = PL.nd[d][ni + e].sl;
                    float cn4[4], hn4[4];
                    #pragma unroll
                    for (int r = 0; r < 4; ++r) {
                        float cprev = 0.0f;
                        if (ps >= 0) {
                            const unsigned p = (r < 2) ? cs[ps].x : cs[ps].y;
                            cprev = (r & 1) ? bfhi(p) : bflo(p);
                        }
                        const float u  = 1.0f + __builtin_amdgcn_exp2f(acc[e][0][r]);
                        const float q  = 1.0f + __builtin_amdgcn_exp2f(acc[e][1][r]);
                        const float v  = 1.0f + __builtin_amdgcn_exp2f(acc[e][2][r]);
                        const float qo = 1.0f + __builtin_amdgcn_exp2f(acc[e][3][r]);
                        const float uv  = u * v;
                        const float num = fmaf(q, v - 2.0f, cprev * uv);
                        const float cn  = num * __builtin_amdgcn_rcpf(q * uv);
                        const float wt  = 1.0f + __builtin_amdgcn_exp2f(TWOL2E * cn);
                        const float h   = (wt - 2.0f) * __builtin_amdgcn_rcpf(qo * wt);
                        cn4[r] = cn; hn4[r] = h;
                        mh[r] = fmaxf(mh[r], h);
                    }
                    if (sl >= 0) {
                        cs[sl].x = pk2(cn4[0], cn4[1]);
                        cs[sl].y = pk2(cn4[2], cn4[3]);
                        union { __hip_bfloat162 h2[2]; uint2 v; } hp;
                        hp.h2[0] = __float22bfloat162_rn(float2{hn4[0], hn4[1]});
                        hp.h2[1] = __float22bfloat162_rn(float2{hn4[2], hn4[3]});
                        *(uint2*)&hs[((sl * 16 + kslot) * NSAMP + m16) * 8
                                     + (quad & 1) * 4] = hp.v;
                    }
                }
            }
        }
    }

    __syncthreads();   // h slots dead; reuse hs for epilogue
    {
        float4 v; v.x = mh[0]; v.y = mh[1]; v.z = mh[2]; v.w = mh[3];
        *(float4*)&s_maxh[m16 * HDIM + w * 16 + quad * 4] = v;
    }
    __syncthreads();

    // ---- FC1: f = t&255, sample half t>>8 (8 samples each) ----
    {
        const int f  = t & 255;
        const int sh = t >> 8;
        float a1[8];
        #pragma unroll
        for (int s = 0; s < 8; ++s) a1[s] = fc1_b[f];
        for (int k4 = 0; k4 < HDIM / 4; ++k4) {
            const float4 wv = *(const float4*)&fc1_W[f * HDIM + k4 * 4];
            #pragma unroll
            for (int s = 0; s < 8; ++s) {
                const float4 h4 = *(const float4*)&s_maxh[(sh * 8 + s) * HDIM + k4 * 4];
                a1[s] += wv.x * h4.x + wv.y * h4.y + wv.z * h4.z + wv.w * h4.w;
            }
        }
        #pragma unroll
        for (int s = 0; s < 8; ++s)
            s_fc1[(sh * 8 + s) * 256 + f] = fmaxf(a1[s], 0.0f);
    }
    __syncthreads();

    if (t < NSAMP * 10) {
        const int s = t / 10, a = t % 10;
        float acc2 = fc2_b[a];
        for (int f4 = 0; f4 < 256 / 4; ++f4) {
            const float4 wv = *(const float4*)&fc2_W[a * 256 + f4 * 4];
            const float4 v  = *(const float4*)&s_fc1[s * 256 + f4 * 4];
            acc2 += wv.x * v.x + wv.y * v.y + wv.z * v.z + wv.w * v.w;
        }
        s_logit[s * 10 + a] = acc2;
    }
    __syncthreads();

    if (t < NSAMP) {
        float m = -1e30f;
        #pragma unroll
        for (int a = 0; a < 10; ++a) m = fmaxf(m, s_logit[t * 10 + a]);
        float sum = 0.0f;
        #pragma unroll
        for (int a = 0; a < 10; ++a) sum += __expf(s_logit[t * 10 + a] - m);
        const float lse = m + __logf(sum);
        #pragma unroll
        for (int a = 0; a < 10; ++a)
            out[(s_base + t) * 10 + a] = s_logit[t * 10 + a] - lse;
    }
}

extern "C" void kernel_launch(void* const* d_in, const int* in_sizes, int n_in,
                              void* d_out, int out_size, void* d_ws, size_t ws_size,
                              hipStream_t stream)
{
    (void)d_ws; (void)ws_size; (void)n_in; (void)out_size;

    const float* x   = (const float*)d_in[0];
    const float* Wih = (const float*)d_in[1];
    const float* Whh = (const float*)d_in[2];
    const float* bih = (const float*)d_in[3];
    const float* bhh = (const float*)d_in[4];
    const float* f1w = (const float*)d_in[5];
    const float* f1b = (const float*)d_in[6];
    const float* f2w = (const float*)d_in[7];
    const float* f2b = (const float*)d_in[8];

    const int mb = in_sizes[0] / (NOBJ * DDIM);   // 8192
    dim3 grid(mb / NSAMP), block(BLOCK);
    subset_lstm_fused_kernel<<<grid, block, 0, stream>>>(
        x, Wih, Whh, bih, bhh, f1w, f1b, f2w, f2b, (float*)d_out);
}